// Round 1
// baseline (325.223 us; speedup 1.0000x reference)
//
#include <hip/hip_runtime.h>
#include <hip/hip_bf16.h>
#include <stdint.h>

#define NG      128      // graphs
#define NN      256      // nodes per graph
#define DF      128      // features
#define KB      16       // bins
#define NINST   256      // 2*NG graph-instances
#define K2      64       // DF/2 (bf16x2 words)
#define STR2    65       // padded row stride in 4B words (130 bf16)

__device__ __forceinline__ uint32_t f2bf(float f) {
    uint32_t u = __float_as_uint(f);
    u += 0x7FFFu + ((u >> 16) & 1u);   // RNE to bf16
    return u >> 16;
}

// 4x4 tile of dot products over 128-dim rows stored as packed bf16x2 in LDS
__device__ __forceinline__ void dot4x4(const uint32_t* __restrict__ sh,
                                       int rowBase, int colBase, float acc[4][4]) {
    #pragma unroll 8
    for (int k2 = 0; k2 < K2; ++k2) {
        float ax[4], ay[4], bx[4], by[4];
        #pragma unroll
        for (int r = 0; r < 4; ++r) {
            uint32_t w = sh[(rowBase + r) * STR2 + k2];
            ax[r] = __uint_as_float(w << 16);
            ay[r] = __uint_as_float(w & 0xFFFF0000u);
        }
        #pragma unroll
        for (int c = 0; c < 4; ++c) {
            uint32_t w = sh[(colBase + c) * STR2 + k2];
            bx[c] = __uint_as_float(w << 16);
            by[c] = __uint_as_float(w & 0xFFFF0000u);
        }
        #pragma unroll
        for (int r = 0; r < 4; ++r)
            #pragma unroll
            for (int c = 0; c < 4; ++c)
                acc[r][c] += ax[r] * bx[c] + ay[r] * by[c];
    }
}

// One block per graph-instance: compute 16-bin soft histogram signature.
__global__ __launch_bounds__(1024)
void uts_kernel(const float* __restrict__ H1, const float* __restrict__ H2,
                float* __restrict__ sig) {
    __shared__ uint32_t sh[NN * STR2];   // 66560 B packed bf16
    __shared__ float    sq[NN];          // row squared norms
    __shared__ float    red[256];        // reduce scratch
    __shared__ float    invm_sh;

    const int b   = blockIdx.x;
    const int tid = threadIdx.x;
    const float* Hsrc = (b < NG) ? (H1 + (size_t)b * NN * DF)
                                 : (H2 + (size_t)(b - NG) * NN * DF);

    // stage: 256 rows x 64 bf16x2 words, coalesced float2 reads
    for (int f = tid; f < NN * K2; f += 1024) {
        int r = f >> 6, k2 = f & 63;
        float2 v = *(const float2*)(Hsrc + r * DF + 2 * k2);
        sh[r * STR2 + k2] = f2bf(v.x) | (f2bf(v.y) << 16);
    }
    __syncthreads();

    // squared norms (same accumulation structure as dot4x4 diagonal)
    if (tid < NN) {
        float s = 0.f;
        for (int k2 = 0; k2 < K2; ++k2) {
            uint32_t w = sh[tid * STR2 + k2];
            float x = __uint_as_float(w << 16);
            float y = __uint_as_float(w & 0xFFFF0000u);
            s += x * x + y * y;
        }
        sq[tid] = s;
    }
    __syncthreads();

    const int tx = tid & 15;        // col group
    const int ty = tid >> 4;        // row group (0..63)
    const int rowBase = ty * 4;
    const int lane = tid & 63, wave = tid >> 6;

    // ---- pass 1: sum of all pairwise distances ----
    float sumD = 0.f;
    for (int s = 0; s < 4; ++s) {
        const int colBase = s * 64 + tx * 4;
        float acc[4][4] = {};
        dot4x4(sh, rowBase, colBase, acc);
        #pragma unroll
        for (int r = 0; r < 4; ++r)
            #pragma unroll
            for (int c = 0; c < 4; ++c) {
                float d2 = sq[rowBase + r] + sq[colBase + c] - 2.f * acc[r][c];
                sumD += sqrtf(fmaxf(d2, 0.f) + 1e-12f);
            }
    }
    #pragma unroll
    for (int off = 32; off > 0; off >>= 1) sumD += __shfl_down(sumD, off, 64);
    if (lane == 0) red[wave] = sumD;
    __syncthreads();
    if (tid == 0) {
        float t = 0.f;
        for (int w = 0; w < 16; ++w) t += red[w];
        invm_sh = 1.f / (t * (1.f / 65536.f) + 1e-8f);
    }
    __syncthreads();
    const float invm = invm_sh;

    // ---- pass 2: histogram ----
    float hist[KB] = {};
    for (int s = 0; s < 4; ++s) {
        const int colBase = s * 64 + tx * 4;
        float acc[4][4] = {};
        dot4x4(sh, rowBase, colBase, acc);
        #pragma unroll
        for (int r = 0; r < 4; ++r)
            #pragma unroll
            for (int c = 0; c < 4; ++c) {
                float d2 = sq[rowBase + r] + sq[colBase + c] - 2.f * acc[r][c];
                float Dn = sqrtf(fmaxf(d2, 0.f) + 1e-12f) * invm;
                #pragma unroll
                for (int k = 0; k < KB; ++k) {
                    float t = Dn - 0.2f * k;              // centers = 0.2*k
                    hist[k] += __expf(-14.2222222f * t * t); // -0.5/sigma^2
                }
            }
    }
    // block-reduce 16 bins
    #pragma unroll
    for (int k = 0; k < KB; ++k) {
        float h = hist[k];
        #pragma unroll
        for (int off = 32; off > 0; off >>= 1) h += __shfl_down(h, off, 64);
        if (lane == 0) red[wave * KB + k] = h;
    }
    __syncthreads();
    if (tid < KB) {
        float h = 0.f;
        for (int w = 0; w < 16; ++w) h += red[w * KB + tid];
        sq[tid] = h;          // sq[] free now: reuse for final hist
    }
    __syncthreads();
    if (tid < KB) {
        float S = 0.f;
        for (int k = 0; k < KB; ++k) S += sq[k];
        sig[b * KB + tid] = sq[tid] / (S + 1e-8f);
    }
}

// NT-Xent: one block per row of the 256x256 similarity matrix.
__global__ __launch_bounds__(256)
void ntx_kernel(const float* __restrict__ z1, const float* __restrict__ z2,
                float* __restrict__ part) {
    __shared__ float zsh[256 * 129];
    __shared__ float red[256];
    __shared__ float slabel;

    const int b = blockIdx.x, t = threadIdx.x;

    for (int f = t; f < 256 * 128; f += 256) {
        int r = f >> 7, k = f & 127;
        float v = (r < 128) ? z1[f] : z2[f - 128 * 128];
        zsh[r * 129 + k] = v;
    }
    __syncthreads();

    const float* zb = &zsh[b * 129];
    const float* zj = &zsh[t * 129];
    float dot = 0.f, sj = 0.f, sb = 0.f;
    #pragma unroll 8
    for (int k = 0; k < 128; ++k) {
        float xb = zb[k], xj = zj[k];
        dot += xb * xj;
        sj  += xj * xj;
        sb  += xb * xb;
    }
    float s = 2.0f * dot / ((sqrtf(sb) + 1e-8f) * (sqrtf(sj) + 1e-8f)); // /TEMP
    if (t == b) s = -1e9f;

    const int label = (b < 128) ? b + 128 : b - 128;
    if (t == label) slabel = s;

    // max reduce
    red[t] = s;
    __syncthreads();
    for (int off = 128; off > 0; off >>= 1) {
        if (t < off) red[t] = fmaxf(red[t], red[t + off]);
        __syncthreads();
    }
    float m = red[0];
    __syncthreads();
    // sum(exp) reduce
    red[t] = __expf(s - m);
    __syncthreads();
    for (int off = 128; off > 0; off >>= 1) {
        if (t < off) red[t] += red[t + off];
        __syncthreads();
    }
    if (t == 0) part[b] = slabel - m - logf(red[0]);
}

__global__ __launch_bounds__(256)
void final_kernel(const float* __restrict__ sig, const float* __restrict__ part,
                  float* __restrict__ out) {
    __shared__ float red[256];
    const int t = threadIdx.x;

    float topo = 0.f;
    if (t < 128) {
        #pragma unroll
        for (int k = 0; k < KB; ++k) {
            float d = sig[t * KB + k] - sig[(t + 128) * KB + k];
            topo += d * d;
        }
    }
    red[t] = topo;
    __syncthreads();
    for (int off = 128; off > 0; off >>= 1) {
        if (t < off) red[t] += red[t + off];
        __syncthreads();
    }
    float topoS = red[0];
    __syncthreads();
    red[t] = part[t];
    __syncthreads();
    for (int off = 128; off > 0; off >>= 1) {
        if (t < off) red[t] += red[t + off];
        __syncthreads();
    }
    if (t == 0)
        out[0] = 0.1f * (topoS * (1.f / 2048.f) - red[0] * (1.f / 256.f));
}

extern "C" void kernel_launch(void* const* d_in, const int* in_sizes, int n_in,
                              void* d_out, int out_size, void* d_ws, size_t ws_size,
                              hipStream_t stream) {
    const float* H1 = (const float*)d_in[0];
    const float* H2 = (const float*)d_in[2];
    const float* z1 = (const float*)d_in[4];
    const float* z2 = (const float*)d_in[5];
    float* ws   = (float*)d_ws;
    float* sig  = ws;          // 256*16 floats
    float* part = ws + 4096;   // 256 floats
    float* out  = (float*)d_out;

    hipLaunchKernelGGL(uts_kernel,   dim3(NINST), dim3(1024), 0, stream, H1, H2, sig);
    hipLaunchKernelGGL(ntx_kernel,   dim3(256),   dim3(256),  0, stream, z1, z2, part);
    hipLaunchKernelGGL(final_kernel, dim3(1),     dim3(256),  0, stream, sig, part, out);
}

// Round 2
// 138.395 us; speedup vs baseline: 2.3500x; 2.3500x over previous
//
#include <hip/hip_runtime.h>
#include <hip/hip_bf16.h>
#include <stdint.h>

#define NG 128
#define NN 256
#define DF 128
#define KB 16

typedef __attribute__((ext_vector_type(8))) short bf16x8;   // 8 bf16 = 4 VGPRs
typedef __attribute__((ext_vector_type(4))) float f32x4;

#define STRW 68   // LDS row stride in words (136 bf16, 272B): 16B-aligned, 17 granules -> conflict-free b128 frag loads

__device__ __forceinline__ uint32_t f2bf(float f) {
    uint32_t u = __float_as_uint(f);
    u += 0x7FFFu + ((u >> 16) & 1u);   // RNE to bf16
    return u >> 16;
}

// One block (1024 thr = 16 waves) per graph-instance.
// Phase 1: stage H as bf16 in LDS. Phase 2: row norms. Phase 3: MFMA Gram,
// convert to distances held in 64 VGPR/lane. Phase 4: mean. Phase 5: histogram
// via bounded Gaussian recurrence (4 exps/pair instead of 16).
__global__ __launch_bounds__(1024)
void uts_kernel(const float* __restrict__ H1, const float* __restrict__ H2,
                float* __restrict__ sig) {
  __shared__ uint32_t sh[NN * STRW];   // 69632 B
  __shared__ float sq[NN];
  __shared__ float red2[1024];
  __shared__ float red[256];
  __shared__ float invm_sh;

  const int b = blockIdx.x, tid = threadIdx.x;
  const float* Hsrc = (b < NG) ? H1 + (size_t)b * NN * DF
                               : H2 + (size_t)(b - NG) * NN * DF;

  // ---- stage: pack fp32 -> bf16x2 words, coalesced ----
  for (int f = tid; f < NN * 64; f += 1024) {
    int r = f >> 6, k2 = f & 63;
    float2 v = *(const float2*)(Hsrc + r * DF + 2 * k2);
    sh[r * STRW + k2] = f2bf(v.x) | (f2bf(v.y) << 16);
  }
  __syncthreads();

  // ---- row squared norms: 4 threads per row (2-way bank alias = free) ----
  {
    int r = tid >> 2, qq = tid & 3;
    float s = 0.f;
    #pragma unroll
    for (int k = 0; k < 16; ++k) {
      uint32_t wv = sh[r * STRW + qq * 16 + k];
      float x = __uint_as_float(wv << 16);
      float y = __uint_as_float(wv & 0xFFFF0000u);
      s += x * x + y * y;
    }
    red2[tid] = s;
  }
  __syncthreads();
  if (tid < NN)
    sq[tid] = red2[tid * 4] + red2[tid * 4 + 1] + red2[tid * 4 + 2] + red2[tid * 4 + 3];
  __syncthreads();

  // ---- MFMA Gram -> distances in registers ----
  const int w = tid >> 6, lane = tid & 63;
  const int wr = w & 3, wc = w >> 2;
  const int R0 = wr * 64, C0 = wc * 64;
  const int n16 = lane & 15, q = lane >> 4;

  float Dv[64];
  float sumD = 0.f;
  #pragma unroll
  for (int ri = 0; ri < 4; ++ri) {
    // A fragments for this 16-row strip, all 4 k-steps (A[m=lane&15][k=q*8+j])
    bf16x8 af[4];
    const int arow = R0 + ri * 16 + n16;
    #pragma unroll
    for (int ks = 0; ks < 4; ++ks)
      af[ks] = *(const bf16x8*)&sh[arow * STRW + ks * 16 + q * 4];
    float sqr[4];
    #pragma unroll
    for (int rg = 0; rg < 4; ++rg) sqr[rg] = sq[R0 + ri * 16 + q * 4 + rg];

    #pragma unroll
    for (int ci = 0; ci < 4; ++ci) {
      const int brow = C0 + ci * 16 + n16;   // B[k][n=lane&15] = H[col-node][k]
      f32x4 acc = {0.f, 0.f, 0.f, 0.f};
      #pragma unroll
      for (int ks = 0; ks < 4; ++ks) {
        bf16x8 bf = *(const bf16x8*)&sh[brow * STRW + ks * 16 + q * 4];
        acc = __builtin_amdgcn_mfma_f32_16x16x32_bf16(af[ks], bf, acc, 0, 0, 0);
      }
      float sqc = sq[C0 + ci * 16 + n16];
      #pragma unroll
      for (int rg = 0; rg < 4; ++rg) {
        // C/D layout: col = lane&15, row = q*4 + rg  (m89-verified)
        float d2 = sqr[rg] + sqc - 2.f * acc[rg];
        float d = sqrtf(fmaxf(d2, 0.f) + 1e-12f);
        Dv[(ri * 4 + ci) * 4 + rg] = d;
        sumD += d;
      }
    }
  }

  // ---- mean ----
  #pragma unroll
  for (int off = 32; off > 0; off >>= 1) sumD += __shfl_down(sumD, off, 64);
  if (lane == 0) red[w] = sumD;
  __syncthreads();
  if (tid == 0) {
    float t = 0.f;
    for (int i = 0; i < 16; ++i) t += red[i];
    invm_sh = 1.f / (t * (1.f / 65536.f) + 1e-8f);
  }
  __syncthreads();
  const float invm = invm_sh;

  // ---- histogram: exp(-a(Dn-ck)^2) = P*Q^k*Rk ; Rk folded at the end.
  // Two half-ranges (centers 0 and 1.6) keep exponents bounded by a*c^2*7^2=27.9.
  float h[KB];
  #pragma unroll
  for (int k = 0; k < KB; ++k) h[k] = 0.f;
  #pragma unroll 4
  for (int i = 0; i < 64; ++i) {
    float Dn = Dv[i] * invm;
    float t8 = Dn - 1.6f;
    float pa = __expf(-14.2222222f * Dn * Dn);
    float qa = __expf(5.68888889f * Dn);
    float pb = __expf(-14.2222222f * t8 * t8);
    float qb = __expf(5.68888889f * t8);
    float wv = pa;
    h[0] += wv; wv *= qa; h[1] += wv; wv *= qa; h[2] += wv; wv *= qa; h[3] += wv;
    wv *= qa; h[4] += wv; wv *= qa; h[5] += wv; wv *= qa; h[6] += wv; wv *= qa; h[7] += wv;
    wv = pb;
    h[8] += wv; wv *= qb; h[9] += wv; wv *= qb; h[10] += wv; wv *= qb; h[11] += wv;
    wv *= qb; h[12] += wv; wv *= qb; h[13] += wv; wv *= qb; h[14] += wv; wv *= qb; h[15] += wv;
  }

  // ---- reduce 16 bins across 64 lanes, then across 16 waves ----
  #pragma unroll
  for (int k = 0; k < KB; ++k) {
    float hv = h[k];
    #pragma unroll
    for (int off = 32; off > 0; off >>= 1) hv += __shfl_down(hv, off, 64);
    if (lane == 0) red[w * KB + k] = hv;
  }
  __syncthreads();
  if (tid < KB) {
    float hv = 0.f;
    for (int i = 0; i < 16; ++i) hv += red[i * KB + tid];
    int j = tid & 7;                       // bin<8: j=bin ; bin>=8: j=bin-8
    red2[tid] = hv * __expf(-0.56888889f * (float)(j * j));   // Rk fold
  }
  __syncthreads();
  if (tid < KB) {
    float S = 0.f;
    for (int k = 0; k < KB; ++k) S += red2[k];
    sig[b * KB + tid] = red2[tid] / (S + 1e-8f);
  }
}

// NT-Xent: one block per row of the 256x256 similarity matrix.
__global__ __launch_bounds__(256)
void ntx_kernel(const float* __restrict__ z1, const float* __restrict__ z2,
                float* __restrict__ part) {
    __shared__ float zsh[256 * 129];
    __shared__ float red[256];
    __shared__ float slabel;

    const int b = blockIdx.x, t = threadIdx.x;

    for (int f = t; f < 256 * 128; f += 256) {
        int r = f >> 7, k = f & 127;
        float v = (r < 128) ? z1[f] : z2[f - 128 * 128];
        zsh[r * 129 + k] = v;
    }
    __syncthreads();

    const float* zb = &zsh[b * 129];
    const float* zj = &zsh[t * 129];
    float dot = 0.f, sj = 0.f, sb = 0.f;
    #pragma unroll 8
    for (int k = 0; k < 128; ++k) {
        float xb = zb[k], xj = zj[k];
        dot += xb * xj;
        sj  += xj * xj;
        sb  += xb * xb;
    }
    float s = 2.0f * dot / ((sqrtf(sb) + 1e-8f) * (sqrtf(sj) + 1e-8f)); // /TEMP
    if (t == b) s = -1e9f;

    const int label = (b < 128) ? b + 128 : b - 128;
    if (t == label) slabel = s;

    red[t] = s;
    __syncthreads();
    for (int off = 128; off > 0; off >>= 1) {
        if (t < off) red[t] = fmaxf(red[t], red[t + off]);
        __syncthreads();
    }
    float m = red[0];
    __syncthreads();
    red[t] = __expf(s - m);
    __syncthreads();
    for (int off = 128; off > 0; off >>= 1) {
        if (t < off) red[t] += red[t + off];
        __syncthreads();
    }
    if (t == 0) part[b] = slabel - m - logf(red[0]);
}

__global__ __launch_bounds__(256)
void final_kernel(const float* __restrict__ sig, const float* __restrict__ part,
                  float* __restrict__ out) {
    __shared__ float red[256];
    const int t = threadIdx.x;

    float topo = 0.f;
    if (t < 128) {
        #pragma unroll
        for (int k = 0; k < KB; ++k) {
            float d = sig[t * KB + k] - sig[(t + 128) * KB + k];
            topo += d * d;
        }
    }
    red[t] = topo;
    __syncthreads();
    for (int off = 128; off > 0; off >>= 1) {
        if (t < off) red[t] += red[t + off];
        __syncthreads();
    }
    float topoS = red[0];
    __syncthreads();
    red[t] = part[t];
    __syncthreads();
    for (int off = 128; off > 0; off >>= 1) {
        if (t < off) red[t] += red[t + off];
        __syncthreads();
    }
    if (t == 0)
        out[0] = 0.1f * (topoS * (1.f / 2048.f) - red[0] * (1.f / 256.f));
}

extern "C" void kernel_launch(void* const* d_in, const int* in_sizes, int n_in,
                              void* d_out, int out_size, void* d_ws, size_t ws_size,
                              hipStream_t stream) {
    const float* H1 = (const float*)d_in[0];
    const float* H2 = (const float*)d_in[2];
    const float* z1 = (const float*)d_in[4];
    const float* z2 = (const float*)d_in[5];
    float* ws   = (float*)d_ws;
    float* sig  = ws;          // 256*16 floats
    float* part = ws + 4096;   // 256 floats
    float* out  = (float*)d_out;

    hipLaunchKernelGGL(uts_kernel,   dim3(256), dim3(1024), 0, stream, H1, H2, sig);
    hipLaunchKernelGGL(ntx_kernel,   dim3(256), dim3(256),  0, stream, z1, z2, part);
    hipLaunchKernelGGL(final_kernel, dim3(1),   dim3(256),  0, stream, sig, part, out);
}